// Round 7
// baseline (1064.754 us; speedup 1.0000x reference)
//
#include <hip/hip_runtime.h>
#include <hip/hip_bf16.h>

constexpr int D    = 128;   // d_model
constexpr int HF   = 256;   // ffn / output dim
constexpr int NH   = 4;
constexpr int DH   = 32;
constexpr int NL   = 3;
constexpr int SEQ  = 1024;
constexpr int NB   = 65;    // 64 support + 1 query
constexpr int NTOK = NB * SEQ;   // 66560
constexpr int NSUP = 64 * SEQ;   // 65536
constexpr int NC   = 10;

using u16 = unsigned short;
using u32 = unsigned int;
typedef __bf16 bf16x8 __attribute__((ext_vector_type(8)));
typedef float  f32x4  __attribute__((ext_vector_type(4)));
typedef float  f32x16 __attribute__((ext_vector_type(16)));
typedef u16    u16x4  __attribute__((ext_vector_type(4)));
typedef u16    u16x8  __attribute__((ext_vector_type(8)));

static __device__ __forceinline__ u16 f2b(float f) {
  return __builtin_bit_cast(u16, (__bf16)f);
}
static __device__ __forceinline__ float b2f(u16 u) {
  return (float)__builtin_bit_cast(__bf16, u);
}

// ---------------- weight f32 -> bf16 ----------------
__global__ __launch_bounds__(256) void k_f2b(const float* __restrict__ in,
                                             u16* __restrict__ out, int n) {
  int i = blockIdx.x * 256 + threadIdx.x;
  if (i < n) out[i] = f2b(in[i]);
}

// ---------------- embedding (f32 x + bf16 xb) ----------------
__global__ __launch_bounds__(256) void k_embed(const int* __restrict__ sup,
                                               const int* __restrict__ qry,
                                               const float* __restrict__ emb,
                                               float* __restrict__ x,
                                               u16* __restrict__ xb) {
  int64_t i = (int64_t)blockIdx.x * 256 + threadIdx.x;
  int tok_i = (int)(i >> 7);
  int d = (int)(i & 127);
  int t = tok_i < NSUP ? sup[tok_i] : qry[tok_i - NSUP];
  float v = emb[t * D + d];
  x[i] = v;
  xb[i] = f2b(v);
}

// ---------------- MFMA GEMM: C[m,n] = sum_k A[m,k]*B[n,k] + bias[n] ----------------
template<bool RELU, bool BF16OUT>
__global__ __launch_bounds__(256) void k_gemm_mfma(const u16* __restrict__ A,
                                                   const u16* __restrict__ B,
                                                   const float* __restrict__ bias,
                                                   void* __restrict__ Cm,
                                                   int M, int N, int K) {
  const int tid = threadIdx.x;
  const int w = tid >> 6, l = tid & 63;
  const int g = l >> 4, c16 = l & 15;
  const int m0 = blockIdx.x * 128 + w * 32;
  const int n0 = blockIdx.y * 128;

  f32x4 acc[2][8] = {};
  const u16* a0p = A + (size_t)(m0 + c16) * K + g * 8;
  const u16* a1p = a0p + (size_t)16 * K;
  const u16* bp  = B + (size_t)(n0 + c16) * K + g * 8;

  for (int k = 0; k < K; k += 32) {
    bf16x8 a0 = *(const bf16x8*)(a0p + k);
    bf16x8 a1 = *(const bf16x8*)(a1p + k);
    #pragma unroll
    for (int nc = 0; nc < 8; ++nc) {
      bf16x8 b = *(const bf16x8*)(bp + (size_t)(nc * 16) * K + k);
      acc[0][nc] = __builtin_amdgcn_mfma_f32_16x16x32_bf16(a0, b, acc[0][nc], 0, 0, 0);
      acc[1][nc] = __builtin_amdgcn_mfma_f32_16x16x32_bf16(a1, b, acc[1][nc], 0, 0, 0);
    }
  }

  #pragma unroll
  for (int nc = 0; nc < 8; ++nc) {
    const int n_ = n0 + nc * 16 + c16;
    const float bs = bias[n_];
    #pragma unroll
    for (int mf = 0; mf < 2; ++mf)
      #pragma unroll
      for (int r = 0; r < 4; ++r) {
        const int m_ = m0 + mf * 16 + g * 4 + r;
        float v = acc[mf][nc][r] + bs;
        if (RELU) v = fmaxf(v, 0.f);
        if (BF16OUT) ((u16*)Cm)[(size_t)m_ * N + n_] = f2b(v);
        else         ((float*)Cm)[(size_t)m_ * N + n_] = v;
      }
  }
}

// ---------------- MFMA flash attention, swapped-operand 32x32 ----------------
// qkvb: bf16 [NTOK][384] = [q|k|v]; out: bf16 [NTOK][128].
// grid (qpair=16, bh=260); block 128 = 2 INDEPENDENT waves (private Vt each),
// each wave owns 32 q rows. Tree reductions + defer-max (THR=8) softmax.
__global__ __launch_bounds__(128) void k_attn_mfma(const u16* __restrict__ qkvb,
                                                   u16* __restrict__ out) {
  const int bh = blockIdx.y;
  const int b = bh >> 2, h = bh & 3;
  const int tid = threadIdx.x;
  const int wv = tid >> 6;        // wave 0/1
  const int l = tid & 63;
  const int q5 = l & 31;
  const int hi = l >> 5;          // lane half
  const int qbase = (blockIdx.x * 2 + wv) * 32;

  __shared__ u16 VtAll[2][32 * 72];   // per-wave V^T: [dh][key], stride 72 u16
  u16* Vt = VtAll[wv];
  u32* Vtw = (u32*)Vt;

  const size_t tok0 = (size_t)b * SEQ;
  constexpr float KSL = 0.25500446f;   // 1/sqrt(32) * log2(e)

  // Q B-fragments: lane holds Q[qbase+q5][dh = hi*8+j] (+16 for second half)
  const u16* qrow = qkvb + (tok0 + qbase + q5) * 384 + h * 32 + hi * 8;
  bf16x8 qf0 = *(const bf16x8*)(qrow);
  bf16x8 qf1 = *(const bf16x8*)(qrow + 16);

  f32x16 acc = {};                // O^T accumulator
  float m = -3.0e38f, lsum = 0.f;

  const u16* kbase = qkvb + tok0 * 384 + 128 + h * 32 + (size_t)q5 * 384 + hi * 8;
  const u16* vbase = qkvb + tok0 * 384 + 256 + h * 32 + hi * 16;
  const f32x16 z16 = {};

  for (int kt = 0; kt < SEQ; kt += 64) {
    // V stage: lane covers rows kt+2*q5, +1; cols hi*16..+16
    const u16* vr0 = vbase + (size_t)(kt + q5 * 2) * 384;
    const u16* vr1 = vr0 + 384;
    u16x8 a_lo = *(const u16x8*)(vr0);
    u16x8 a_hi = *(const u16x8*)(vr0 + 8);
    u16x8 b_lo = *(const u16x8*)(vr1);
    u16x8 b_hi = *(const u16x8*)(vr1 + 8);
    // K A-fragments: rows kt+q5 (+32), k-slot dh = hi*8+j (+16)
    const u16* kr = kbase + (size_t)kt * 384;
    bf16x8 k00 = *(const bf16x8*)(kr);
    bf16x8 k01 = *(const bf16x8*)(kr + 16);
    bf16x8 k10 = *(const bf16x8*)(kr + (size_t)32 * 384);
    bf16x8 k11 = *(const bf16x8*)(kr + (size_t)32 * 384 + 16);

    #pragma unroll
    for (int j = 0; j < 8; ++j) {
      Vtw[(hi * 16 + j) * 36 + q5]     = (u32)a_lo[j] | ((u32)b_lo[j] << 16);
      Vtw[(hi * 16 + 8 + j) * 36 + q5] = (u32)a_hi[j] | ((u32)b_hi[j] << 16);
    }
    __threadfence_block();
    __builtin_amdgcn_sched_barrier(0);

    // S^T: two 32-key subtiles
    f32x16 s0 = __builtin_amdgcn_mfma_f32_32x32x16_bf16(k00, qf0, z16, 0, 0, 0);
    s0 = __builtin_amdgcn_mfma_f32_32x32x16_bf16(k01, qf1, s0, 0, 0, 0);
    f32x16 s1 = __builtin_amdgcn_mfma_f32_32x32x16_bf16(k10, qf0, z16, 0, 0, 0);
    s1 = __builtin_amdgcn_mfma_f32_32x32x16_bf16(k11, qf1, s1, 0, 0, 0);

    // tile max (tree, depth ~5)
    float r8[8];
    #pragma unroll
    for (int i = 0; i < 8; ++i)
      r8[i] = fmaxf(fmaxf(s0[i], s0[i + 8]), fmaxf(s1[i], s1[i + 8]));
    float mx = fmaxf(fmaxf(fmaxf(r8[0], r8[1]), fmaxf(r8[2], r8[3])),
                     fmaxf(fmaxf(r8[4], r8[5]), fmaxf(r8[6], r8[7])));
    mx = fmaxf(mx, __shfl_xor(mx, 32));
    float mxk = mx * KSL;

    // defer-max: rescale only when tile max exceeds running m by >8 (log2 domain)
    if (__any(mxk > m + 8.f)) {
      float mn = fmaxf(m, mxk);
      float c0 = exp2f(m - mn);
      m = mn;
      lsum *= c0;
      #pragma unroll
      for (int i = 0; i < 16; ++i) acc[i] *= c0;
    }

    float p0[16], p1[16];
    #pragma unroll
    for (int i = 0; i < 16; ++i) p0[i] = exp2f(fmaf(s0[i], KSL, -m));
    #pragma unroll
    for (int i = 0; i < 16; ++i) p1[i] = exp2f(fmaf(s1[i], KSL, -m));

    // sum (tree)
    float t8[8];
    #pragma unroll
    for (int i = 0; i < 8; ++i)
      t8[i] = (p0[i] + p0[i + 8]) + (p1[i] + p1[i + 8]);
    float ps = ((t8[0] + t8[1]) + (t8[2] + t8[3])) + ((t8[4] + t8[5]) + (t8[6] + t8[7]));
    ps += __shfl_xor(ps, 32);
    lsum += ps;

    // pack P pairs to bf16 words
    u32 pk0[8], pk1[8];
    #pragma unroll
    for (int mi = 0; mi < 8; ++mi) {
      pk0[mi] = (u32)f2b(p0[2 * mi]) | ((u32)f2b(p0[2 * mi + 1]) << 16);
      pk1[mi] = (u32)f2b(p1[2 * mi]) | ((u32)f2b(p1[2 * mi + 1]) << 16);
    }

    // PV: per subtile t (32 keys), per half hh (16 keys): exchange lane halves
    #pragma unroll
    for (int t = 0; t < 2; ++t) {
      #pragma unroll
      for (int hh = 0; hh < 2; ++hh) {
        u32 w0s = t ? pk1[4 * hh + 0] : pk0[4 * hh + 0];
        u32 w1s = t ? pk1[4 * hh + 1] : pk0[4 * hh + 1];
        u32 w2s = t ? pk1[4 * hh + 2] : pk0[4 * hh + 2];
        u32 w3s = t ? pk1[4 * hh + 3] : pk0[4 * hh + 3];
        u32 w0x = __shfl_xor(w0s, 32);
        u32 w1x = __shfl_xor(w1s, 32);
        u32 w2x = __shfl_xor(w2s, 32);
        u32 w3x = __shfl_xor(w3s, 32);
        union { u32 w[4]; bf16x8 v; } pf;
        pf.w[0] = hi ? w2x : w0s;
        pf.w[1] = hi ? w3x : w1s;
        pf.w[2] = hi ? w2s : w0x;
        pf.w[3] = hi ? w3s : w1x;
        bf16x8 vf = *(const bf16x8*)(Vt + (size_t)q5 * 72 + t * 32 + hh * 16 + hi * 8);
        acc = __builtin_amdgcn_mfma_f32_32x32x16_bf16(vf, pf.v, acc, 0, 0, 0);
      }
    }
    __threadfence_block();
    __builtin_amdgcn_sched_barrier(0);
  }

  // epilogue: lane writes row q=qbase+q5, dh = (r&3)+8*(r>>2)+4*hi
  float inv = 1.f / lsum;
  u16* orow = out + (tok0 + qbase + q5) * 128 + h * 32 + hi * 4;
  #pragma unroll
  for (int a = 0; a < 4; ++a) {
    u16x4 st;
    #pragma unroll
    for (int j = 0; j < 4; ++j) st[j] = f2b(acc[a * 4 + j] * inv);
    *(u16x4*)(orow + a * 8) = st;
  }
}

// ---------------- residual add + LayerNorm (x f32 in/out, xb bf16 out) ----------------
__global__ __launch_bounds__(256) void k_add_ln(float* __restrict__ x,
                                                u16* __restrict__ xb,
                                                const float* __restrict__ y,
                                                const float* __restrict__ gamma,
                                                const float* __restrict__ beta) {
  int row = blockIdx.x * 4 + (threadIdx.x >> 6);
  int lane = threadIdx.x & 63;
  float* xr = x + (size_t)row * D;
  const float* yr = y + (size_t)row * D;
  float2 v = *(float2*)(xr + lane * 2);
  float2 w = *(const float2*)(yr + lane * 2);
  float a = v.x + w.x, b = v.y + w.y;
  float sum = a + b;
  #pragma unroll
  for (int off = 32; off; off >>= 1) sum += __shfl_xor(sum, off);
  float mean = sum * (1.f / 128.f);
  float da = a - mean, db = b - mean;
  float vs = da * da + db * db;
  #pragma unroll
  for (int off = 32; off; off >>= 1) vs += __shfl_xor(vs, off);
  float inv = 1.f / sqrtf(vs * (1.f / 128.f) + 1e-5f);
  float2 o;
  o.x = da * inv * gamma[lane * 2 + 0] + beta[lane * 2 + 0];
  o.y = db * inv * gamma[lane * 2 + 1] + beta[lane * 2 + 1];
  *(float2*)(xr + lane * 2) = o;
  u32 pk = (u32)f2b(o.x) | ((u32)f2b(o.y) << 16);
  *(u32*)(xb + (size_t)row * D + lane * 2) = pk;
}

// ---------------- prototype accumulation (bf16 feat) ----------------
__global__ __launch_bounds__(256) void k_proto_accum(const u16* __restrict__ feat,
                                                     const int* __restrict__ cls,
                                                     const int* __restrict__ msk,
                                                     float* __restrict__ psum,
                                                     int* __restrict__ pcnt) {
  __shared__ float ls[NC][HF];
  __shared__ int lc[NC];
  int tid = threadIdx.x;
  #pragma unroll
  for (int c = 0; c < NC; ++c) ls[c][tid] = 0.f;
  if (tid < NC) lc[tid] = 0;
  __syncthreads();
  int t0 = blockIdx.x * 256;
  for (int t = t0; t < t0 + 256; ++t) {
    int cl = cls[t];
    int mk = msk[t];
    if (mk > 0 && cl < NC) {
      ls[cl][tid] += b2f(feat[(size_t)t * HF + tid]);
      if (tid == 0) lc[cl]++;
    }
  }
  __syncthreads();
  for (int c = 0; c < NC; ++c) atomicAdd(&psum[c * HF + tid], ls[c][tid]);
  if (tid < NC) atomicAdd(&pcnt[tid], lc[tid]);
}

__global__ void k_proto_final(const float* __restrict__ psum,
                              const int* __restrict__ pcnt,
                              float* __restrict__ protos) {
  int c = blockIdx.x, h = threadIdx.x;
  int n = pcnt[c];
  protos[c * HF + h] = (n > 0) ? psum[c * HF + h] / (float)n : 0.f;
}

// ---------------- logits ----------------
__global__ __launch_bounds__(256) void k_logits(const u16* __restrict__ feat,
                                                const float* __restrict__ protos,
                                                float* __restrict__ out) {
  int i = blockIdx.x * 256 + threadIdx.x;
  if (i >= SEQ * NC) return;
  int s = i / NC, c = i % NC;
  const u16* qf = feat + (size_t)(NSUP + s) * HF;
  const float* pr = protos + c * HF;
  float acc = 0.f;
  #pragma unroll 8
  for (int h = 0; h < HF; ++h) {
    float d = b2f(qf[h]) - pr[h];
    acc += d * d;
  }
  out[i] = -acc;
}

extern "C" void kernel_launch(void* const* d_in, const int* in_sizes, int n_in,
                              void* d_out, int out_size, void* d_ws, size_t ws_size,
                              hipStream_t stream) {
  const int*   sup_in  = (const int*)d_in[0];
  const int*   sup_out = (const int*)d_in[1];
  const int*   qry_in  = (const int*)d_in[2];
  const int*   sup_msk = (const int*)d_in[3];
  const float* emb     = (const float*)d_in[4];
  const float* Wqkv    = (const float*)d_in[5];
  const float* bqkv    = (const float*)d_in[6];
  const float* Wo      = (const float*)d_in[7];
  const float* bo      = (const float*)d_in[8];
  const float* ln1s    = (const float*)d_in[9];
  const float* ln1b    = (const float*)d_in[10];
  const float* W1      = (const float*)d_in[11];
  const float* b1      = (const float*)d_in[12];
  const float* W2      = (const float*)d_in[13];
  const float* b2      = (const float*)d_in[14];
  const float* ln2s    = (const float*)d_in[15];
  const float* ln2b    = (const float*)d_in[16];
  const float* Wp      = (const float*)d_in[17];
  const float* bp      = (const float*)d_in[18];

  float* ws = (float*)d_ws;
  float* x  = ws;
  float* y  = x + (size_t)NTOK * D;
  u16*   xb = (u16*)(y + (size_t)NTOK * D);
  u16*   yb = xb + (size_t)NTOK * D;
  u16*   U  = yb + (size_t)NTOK * D;            // NTOK*384 u16
  u16*   qkvb = U;
  u16*   midb = U;
  u16*   featb = U;
  u16*   wqkvb = U + (size_t)NTOK * 384;
  u16*   wob   = wqkvb + 3 * 384 * 128;
  u16*   w1b   = wob + 3 * 128 * 128;
  u16*   w2b   = w1b + 3 * 256 * 128;
  u16*   wpb   = w2b + 3 * 128 * 256;
  float* psum  = (float*)(((size_t)(wpb + 256 * 128) + 15) & ~(size_t)15);
  int*   pcnt  = (int*)(psum + NC * HF);
  float* protos = psum + NC * HF + 16;
  float* outp = (float*)d_out;

  hipMemsetAsync(psum, 0, NC * HF * sizeof(float) + 16 * sizeof(int), stream);

  k_f2b<<<dim3((3*384*128 + 255)/256), 256, 0, stream>>>(Wqkv, wqkvb, 3*384*128);
  k_f2b<<<dim3((3*128*128 + 255)/256), 256, 0, stream>>>(Wo,   wob,   3*128*128);
  k_f2b<<<dim3((3*256*128 + 255)/256), 256, 0, stream>>>(W1,   w1b,   3*256*128);
  k_f2b<<<dim3((3*128*256 + 255)/256), 256, 0, stream>>>(W2,   w2b,   3*128*256);
  k_f2b<<<dim3((256*128   + 255)/256), 256, 0, stream>>>(Wp,   wpb,   256*128);

  k_embed<<<dim3((NTOK * D) / 256), 256, 0, stream>>>(sup_in, qry_in, emb, x, xb);

  for (int l = 0; l < NL; ++l) {
    k_gemm_mfma<false, true><<<dim3(NTOK / 128, 3), 256, 0, stream>>>(
        xb, wqkvb + (size_t)l * 384 * 128, bqkv + l * 384, qkvb, NTOK, 384, D);
    k_attn_mfma<<<dim3(16, NB * NH), 128, 0, stream>>>(qkvb, yb);
    k_gemm_mfma<false, false><<<dim3(NTOK / 128, 1), 256, 0, stream>>>(
        yb, wob + (size_t)l * 128 * 128, bo + l * D, y, NTOK, D, D);
    k_add_ln<<<dim3(NTOK / 4), 256, 0, stream>>>(x, xb, y, ln1s + l * D, ln1b + l * D);
    k_gemm_mfma<true, true><<<dim3(NTOK / 128, 2), 256, 0, stream>>>(
        xb, w1b + (size_t)l * 256 * 128, b1 + l * HF, midb, NTOK, HF, D);
    k_gemm_mfma<false, false><<<dim3(NTOK / 128, 1), 256, 0, stream>>>(
        midb, w2b + (size_t)l * 128 * 256, b2 + l * D, y, NTOK, D, HF);
    k_add_ln<<<dim3(NTOK / 4), 256, 0, stream>>>(x, xb, y, ln2s + l * D, ln2b + l * D);
  }

  k_gemm_mfma<false, true><<<dim3(NTOK / 128, 2), 256, 0, stream>>>(
      xb, wpb, bp, featb, NTOK, HF, D);
  k_proto_accum<<<dim3(NSUP / 256), 256, 0, stream>>>(featb, sup_out, sup_msk, psum, pcnt);
  k_proto_final<<<dim3(NC), 256, 0, stream>>>(psum, pcnt, protos);
  k_logits<<<dim3((SEQ * NC + 255) / 256), 256, 0, stream>>>(featb, protos, outp);
}

// Round 8
// 999.461 us; speedup vs baseline: 1.0653x; 1.0653x over previous
//
#include <hip/hip_runtime.h>
#include <hip/hip_bf16.h>

constexpr int D    = 128;   // d_model
constexpr int HF   = 256;   // ffn / out dim
constexpr int NH   = 4;
constexpr int DH   = 32;
constexpr int NL   = 3;
constexpr int SEQ  = 1024;
constexpr int NB   = 65;    // 64 support + 1 query
constexpr int NTOK = NB * SEQ;   // 66560
constexpr int NSUP = 64 * SEQ;   // 65536
constexpr int NC   = 10;

using u16 = unsigned short;
using u32 = unsigned int;
typedef __bf16 bf16x8 __attribute__((ext_vector_type(8)));
typedef float  f32x4  __attribute__((ext_vector_type(4)));
typedef float  f32x16 __attribute__((ext_vector_type(16)));
typedef u16    u16x4  __attribute__((ext_vector_type(4)));
typedef u16    u16x8  __attribute__((ext_vector_type(8)));

static __device__ __forceinline__ u16 f2b(float f) {
  return __builtin_bit_cast(u16, (__bf16)f);
}
static __device__ __forceinline__ float b2f(u16 u) {
  return (float)__builtin_bit_cast(__bf16, u);
}

// ---------------- weight f32 -> bf16 ----------------
__global__ __launch_bounds__(256) void k_f2b(const float* __restrict__ in,
                                             u16* __restrict__ out, int n) {
  int i = blockIdx.x * 256 + threadIdx.x;
  if (i < n) out[i] = f2b(in[i]);
}

// ---------------- embedding -> bf16 x ----------------
__global__ __launch_bounds__(256) void k_embed(const int* __restrict__ sup,
                                               const int* __restrict__ qry,
                                               const float* __restrict__ emb,
                                               u32* __restrict__ xbw) {
  int i = blockIdx.x * 256 + threadIdx.x;          // over NTOK*64
  int tok = i >> 6;
  int d2 = (i & 63) * 2;
  int t = tok < NSUP ? sup[tok] : qry[tok - NSUP];
  float2 e = *(const float2*)(emb + t * D + d2);
  xbw[i] = (u32)f2b(e.x) | ((u32)f2b(e.y) << 16);
}

// ---------------- MFMA GEMM: C[m,n] = sum_k A[m,k]*B[n,k] + bias[n] ----------------
template<bool RELU, bool BF16OUT>
__global__ __launch_bounds__(256) void k_gemm_mfma(const u16* __restrict__ A,
                                                   const u16* __restrict__ B,
                                                   const float* __restrict__ bias,
                                                   void* __restrict__ Cm,
                                                   int M, int N, int K) {
  const int tid = threadIdx.x;
  const int w = tid >> 6, l = tid & 63;
  const int g = l >> 4, c16 = l & 15;
  const int m0 = blockIdx.x * 128 + w * 32;
  const int n0 = blockIdx.y * 128;

  f32x4 acc[2][8] = {};
  const u16* a0p = A + (size_t)(m0 + c16) * K + g * 8;
  const u16* a1p = a0p + (size_t)16 * K;
  const u16* bp  = B + (size_t)(n0 + c16) * K + g * 8;

  for (int k = 0; k < K; k += 32) {
    bf16x8 a0 = *(const bf16x8*)(a0p + k);
    bf16x8 a1 = *(const bf16x8*)(a1p + k);
    #pragma unroll
    for (int nc = 0; nc < 8; ++nc) {
      bf16x8 b = *(const bf16x8*)(bp + (size_t)(nc * 16) * K + k);
      acc[0][nc] = __builtin_amdgcn_mfma_f32_16x16x32_bf16(a0, b, acc[0][nc], 0, 0, 0);
      acc[1][nc] = __builtin_amdgcn_mfma_f32_16x16x32_bf16(a1, b, acc[1][nc], 0, 0, 0);
    }
  }

  #pragma unroll
  for (int nc = 0; nc < 8; ++nc) {
    const int n_ = n0 + nc * 16 + c16;
    const float bs = bias[n_];
    #pragma unroll
    for (int mf = 0; mf < 2; ++mf)
      #pragma unroll
      for (int r = 0; r < 4; ++r) {
        const int m_ = m0 + mf * 16 + g * 4 + r;
        float v = acc[mf][nc][r] + bs;
        if (RELU) v = fmaxf(v, 0.f);
        if (BF16OUT) ((u16*)Cm)[(size_t)m_ * N + n_] = f2b(v);
        else         ((float*)Cm)[(size_t)m_ * N + n_] = v;
      }
  }
}

// ---------------- MFMA flash attention: 4 heads/block, XCD-pinned batches -----
// qkvb: bf16 [NTOK][384] = [q|k|v]; out: bf16 [NTOK][128].
// 1-D grid 2304: b=(i&7)+8*((i>>3)>>5), qt=(i>>3)&31 -> all 32 q-tile blocks of
// a batch land on one XCD (i%8), K/V panel L2-resident. Block = 4 autonomous
// waves, wave = head (L1 line sharing across head pairs). No cross-wave sync.
__global__ __launch_bounds__(256) void k_attn_mfma(const u16* __restrict__ qkvb,
                                                   u16* __restrict__ out) {
  const int i = blockIdx.x;
  const int b = (i & 7) + (((i >> 3) >> 5) << 3);
  if (b >= NB) return;
  const int qt = (i >> 3) & 31;
  const int tid = threadIdx.x;
  const int h = tid >> 6;         // wave = head
  const int l = tid & 63;
  const int q5 = l & 31;
  const int hi = l >> 5;          // lane half
  const int qbase = qt * 32;

  // per-wave slice 4864 u16 (2304 used); 38912 B total -> 4 blocks/CU
  __shared__ u16 VtAll[4][4864];
  u16* Vt = VtAll[h];
  u32* Vtw = (u32*)Vt;

  const size_t tok0 = (size_t)b * SEQ;
  constexpr float KSL = 0.25500446f;   // 1/sqrt(32) * log2(e)

  const u16* qrow = qkvb + (tok0 + qbase + q5) * 384 + h * 32 + hi * 8;
  bf16x8 qf0 = *(const bf16x8*)(qrow);
  bf16x8 qf1 = *(const bf16x8*)(qrow + 16);

  f32x16 acc = {};                // O^T accumulator
  float m = -3.0e38f, lsum = 0.f;

  const u16* kbase = qkvb + tok0 * 384 + 128 + h * 32 + (size_t)q5 * 384 + hi * 8;
  const u16* vbase = qkvb + tok0 * 384 + 256 + h * 32 + hi * 16;
  const f32x16 z16 = {};

  for (int kt = 0; kt < SEQ; kt += 64) {
    const u16* vr0 = vbase + (size_t)(kt + q5 * 2) * 384;
    const u16* vr1 = vr0 + 384;
    u16x8 a_lo = *(const u16x8*)(vr0);
    u16x8 a_hi = *(const u16x8*)(vr0 + 8);
    u16x8 b_lo = *(const u16x8*)(vr1);
    u16x8 b_hi = *(const u16x8*)(vr1 + 8);
    const u16* kr = kbase + (size_t)kt * 384;
    bf16x8 k00 = *(const bf16x8*)(kr);
    bf16x8 k01 = *(const bf16x8*)(kr + 16);
    bf16x8 k10 = *(const bf16x8*)(kr + (size_t)32 * 384);
    bf16x8 k11 = *(const bf16x8*)(kr + (size_t)32 * 384 + 16);

    #pragma unroll
    for (int j = 0; j < 8; ++j) {
      Vtw[(hi * 16 + j) * 36 + q5]     = (u32)a_lo[j] | ((u32)b_lo[j] << 16);
      Vtw[(hi * 16 + 8 + j) * 36 + q5] = (u32)a_hi[j] | ((u32)b_hi[j] << 16);
    }
    __threadfence_block();
    __builtin_amdgcn_sched_barrier(0);

    f32x16 s0 = __builtin_amdgcn_mfma_f32_32x32x16_bf16(k00, qf0, z16, 0, 0, 0);
    s0 = __builtin_amdgcn_mfma_f32_32x32x16_bf16(k01, qf1, s0, 0, 0, 0);
    f32x16 s1 = __builtin_amdgcn_mfma_f32_32x32x16_bf16(k10, qf0, z16, 0, 0, 0);
    s1 = __builtin_amdgcn_mfma_f32_32x32x16_bf16(k11, qf1, s1, 0, 0, 0);

    float r8[8];
    #pragma unroll
    for (int ii = 0; ii < 8; ++ii)
      r8[ii] = fmaxf(fmaxf(s0[ii], s0[ii + 8]), fmaxf(s1[ii], s1[ii + 8]));
    float mx = fmaxf(fmaxf(fmaxf(r8[0], r8[1]), fmaxf(r8[2], r8[3])),
                     fmaxf(fmaxf(r8[4], r8[5]), fmaxf(r8[6], r8[7])));
    mx = fmaxf(mx, __shfl_xor(mx, 32));
    float mxk = mx * KSL;

    if (__any(mxk > m + 8.f)) {
      float mn = fmaxf(m, mxk);
      float c0 = exp2f(m - mn);
      m = mn;
      lsum *= c0;
      #pragma unroll
      for (int ii = 0; ii < 16; ++ii) acc[ii] *= c0;
    }

    float p0[16], p1[16];
    #pragma unroll
    for (int ii = 0; ii < 16; ++ii) p0[ii] = exp2f(fmaf(s0[ii], KSL, -m));
    #pragma unroll
    for (int ii = 0; ii < 16; ++ii) p1[ii] = exp2f(fmaf(s1[ii], KSL, -m));

    float t8[8];
    #pragma unroll
    for (int ii = 0; ii < 8; ++ii)
      t8[ii] = (p0[ii] + p0[ii + 8]) + (p1[ii] + p1[ii + 8]);
    float ps = ((t8[0] + t8[1]) + (t8[2] + t8[3])) + ((t8[4] + t8[5]) + (t8[6] + t8[7]));
    ps += __shfl_xor(ps, 32);
    lsum += ps;

    u32 pk0[8], pk1[8];
    #pragma unroll
    for (int mi = 0; mi < 8; ++mi) {
      pk0[mi] = (u32)f2b(p0[2 * mi]) | ((u32)f2b(p0[2 * mi + 1]) << 16);
      pk1[mi] = (u32)f2b(p1[2 * mi]) | ((u32)f2b(p1[2 * mi + 1]) << 16);
    }

    #pragma unroll
    for (int t = 0; t < 2; ++t) {
      #pragma unroll
      for (int hh = 0; hh < 2; ++hh) {
        u32 w0s = t ? pk1[4 * hh + 0] : pk0[4 * hh + 0];
        u32 w1s = t ? pk1[4 * hh + 1] : pk0[4 * hh + 1];
        u32 w2s = t ? pk1[4 * hh + 2] : pk0[4 * hh + 2];
        u32 w3s = t ? pk1[4 * hh + 3] : pk0[4 * hh + 3];
        u32 w0x = __shfl_xor(w0s, 32);
        u32 w1x = __shfl_xor(w1s, 32);
        u32 w2x = __shfl_xor(w2s, 32);
        u32 w3x = __shfl_xor(w3s, 32);
        union { u32 w[4]; bf16x8 v; } pf;
        pf.w[0] = hi ? w2x : w0s;
        pf.w[1] = hi ? w3x : w1s;
        pf.w[2] = hi ? w2s : w0x;
        pf.w[3] = hi ? w3s : w1x;
        bf16x8 vf = *(const bf16x8*)(Vt + (size_t)q5 * 72 + t * 32 + hh * 16 + hi * 8);
        acc = __builtin_amdgcn_mfma_f32_32x32x16_bf16(vf, pf.v, acc, 0, 0, 0);
      }
    }
    __threadfence_block();
    __builtin_amdgcn_sched_barrier(0);
  }

  float inv = 1.f / lsum;
  u16* orow = out + (tok0 + qbase + q5) * 128 + h * 32 + hi * 4;
  #pragma unroll
  for (int a = 0; a < 4; ++a) {
    u16x4 st;
    #pragma unroll
    for (int j = 0; j < 4; ++j) st[j] = f2b(acc[a * 4 + j] * inv);
    *(u16x4*)(orow + a * 8) = st;
  }
}

// ---------------- residual add + LayerNorm (bf16 stream, f32 math) ----------------
__global__ __launch_bounds__(256) void k_add_ln(u16* __restrict__ xb,
                                                const u16* __restrict__ yb,
                                                const float* __restrict__ gamma,
                                                const float* __restrict__ beta) {
  int row = blockIdx.x * 4 + (threadIdx.x >> 6);
  int lane = threadIdx.x & 63;
  u32* xr = (u32*)(xb + (size_t)row * D);
  const u32* yr = (const u32*)(yb + (size_t)row * D);
  u32 xv = xr[lane], yv = yr[lane];
  float a = b2f((u16)(xv & 0xffff)) + b2f((u16)(yv & 0xffff));
  float b = b2f((u16)(xv >> 16))    + b2f((u16)(yv >> 16));
  float sum = a + b;
  #pragma unroll
  for (int off = 32; off; off >>= 1) sum += __shfl_xor(sum, off);
  float mean = sum * (1.f / 128.f);
  float da = a - mean, db = b - mean;
  float vs = da * da + db * db;
  #pragma unroll
  for (int off = 32; off; off >>= 1) vs += __shfl_xor(vs, off);
  float inv = 1.f / sqrtf(vs * (1.f / 128.f) + 1e-5f);
  float ox = da * inv * gamma[lane * 2 + 0] + beta[lane * 2 + 0];
  float oy = db * inv * gamma[lane * 2 + 1] + beta[lane * 2 + 1];
  xr[lane] = (u32)f2b(ox) | ((u32)f2b(oy) << 16);
}

// ---------------- prototype accumulation (bf16 feat) ----------------
__global__ __launch_bounds__(256) void k_proto_accum(const u16* __restrict__ feat,
                                                     const int* __restrict__ cls,
                                                     const int* __restrict__ msk,
                                                     float* __restrict__ psum,
                                                     int* __restrict__ pcnt) {
  __shared__ float ls[NC][HF];
  __shared__ int lc[NC];
  int tid = threadIdx.x;
  #pragma unroll
  for (int c = 0; c < NC; ++c) ls[c][tid] = 0.f;
  if (tid < NC) lc[tid] = 0;
  __syncthreads();
  int t0 = blockIdx.x * 256;
  for (int t = t0; t < t0 + 256; ++t) {
    int cl = cls[t];
    int mk = msk[t];
    if (mk > 0 && cl < NC) {
      ls[cl][tid] += b2f(feat[(size_t)t * HF + tid]);
      if (tid == 0) lc[cl]++;
    }
  }
  __syncthreads();
  for (int c = 0; c < NC; ++c) atomicAdd(&psum[c * HF + tid], ls[c][tid]);
  if (tid < NC) atomicAdd(&pcnt[tid], lc[tid]);
}

__global__ void k_proto_final(const float* __restrict__ psum,
                              const int* __restrict__ pcnt,
                              float* __restrict__ protos) {
  int c = blockIdx.x, h = threadIdx.x;
  int n = pcnt[c];
  protos[c * HF + h] = (n > 0) ? psum[c * HF + h] / (float)n : 0.f;
}

// ---------------- logits ----------------
__global__ __launch_bounds__(256) void k_logits(const u16* __restrict__ feat,
                                                const float* __restrict__ protos,
                                                float* __restrict__ out) {
  int i = blockIdx.x * 256 + threadIdx.x;
  if (i >= SEQ * NC) return;
  int s = i / NC, c = i % NC;
  const u16* qf = feat + (size_t)(NSUP + s) * HF;
  const float* pr = protos + c * HF;
  float acc = 0.f;
  #pragma unroll 8
  for (int h = 0; h < HF; ++h) {
    float d = b2f(qf[h]) - pr[h];
    acc += d * d;
  }
  out[i] = -acc;
}

extern "C" void kernel_launch(void* const* d_in, const int* in_sizes, int n_in,
                              void* d_out, int out_size, void* d_ws, size_t ws_size,
                              hipStream_t stream) {
  const int*   sup_in  = (const int*)d_in[0];
  const int*   sup_out = (const int*)d_in[1];
  const int*   qry_in  = (const int*)d_in[2];
  const int*   sup_msk = (const int*)d_in[3];
  const float* emb     = (const float*)d_in[4];
  const float* Wqkv    = (const float*)d_in[5];
  const float* bqkv    = (const float*)d_in[6];
  const float* Wo      = (const float*)d_in[7];
  const float* bo      = (const float*)d_in[8];
  const float* ln1s    = (const float*)d_in[9];
  const float* ln1b    = (const float*)d_in[10];
  const float* W1      = (const float*)d_in[11];
  const float* b1      = (const float*)d_in[12];
  const float* W2      = (const float*)d_in[13];
  const float* b2      = (const float*)d_in[14];
  const float* ln2s    = (const float*)d_in[15];
  const float* ln2b    = (const float*)d_in[16];
  const float* Wp      = (const float*)d_in[17];
  const float* bp      = (const float*)d_in[18];

  // bf16 stream: xb[NTOK,128] | yb[NTOK,128] | wo_out[NTOK,128] | U[NTOK,384] | weights
  u16* xb = (u16*)d_ws;
  u16* yb = xb + (size_t)NTOK * D;
  u16* zb = yb + (size_t)NTOK * D;              // Wo output
  u16* U  = zb + (size_t)NTOK * D;
  u16* qkvb  = U;                                // [NTOK,384]
  u16* midb  = U;                                // [NTOK,256] (qkvb dead)
  u16* featb = U;                                // [NTOK,256]
  u16* wqkvb = U + (size_t)NTOK * 384;
  u16* wob   = wqkvb + 3 * 384 * 128;
  u16* w1b   = wob + 3 * 128 * 128;
  u16* w2b   = w1b + 3 * 256 * 128;
  u16* wpb   = w2b + 3 * 128 * 256;
  float* psum  = (float*)(((size_t)(wpb + 256 * 128) + 15) & ~(size_t)15);
  int*   pcnt  = (int*)(psum + NC * HF);
  float* protos = psum + NC * HF + 16;
  float* outp = (float*)d_out;

  hipMemsetAsync(psum, 0, NC * HF * sizeof(float) + 16 * sizeof(int), stream);

  k_f2b<<<dim3((3*384*128 + 255)/256), 256, 0, stream>>>(Wqkv, wqkvb, 3*384*128);
  k_f2b<<<dim3((3*128*128 + 255)/256), 256, 0, stream>>>(Wo,   wob,   3*128*128);
  k_f2b<<<dim3((3*256*128 + 255)/256), 256, 0, stream>>>(W1,   w1b,   3*256*128);
  k_f2b<<<dim3((3*128*256 + 255)/256), 256, 0, stream>>>(W2,   w2b,   3*128*256);
  k_f2b<<<dim3((256*128   + 255)/256), 256, 0, stream>>>(Wp,   wpb,   256*128);

  k_embed<<<dim3((NTOK * 64) / 256), 256, 0, stream>>>(sup_in, qry_in, emb, (u32*)xb);

  for (int l = 0; l < NL; ++l) {
    // QKV: xb -> qkvb
    k_gemm_mfma<false, true><<<dim3(NTOK / 128, 3), 256, 0, stream>>>(
        xb, wqkvb + (size_t)l * 384 * 128, bqkv + l * 384, qkvb, NTOK, 384, D);
    // attention: qkvb -> yb
    k_attn_mfma<<<dim3(2304), 256, 0, stream>>>(qkvb, yb);
    // Wo: yb -> zb
    k_gemm_mfma<false, true><<<dim3(NTOK / 128, 1), 256, 0, stream>>>(
        yb, wob + (size_t)l * 128 * 128, bo + l * D, zb, NTOK, D, D);
    // x = LN(x + zb)
    k_add_ln<<<dim3(NTOK / 4), 256, 0, stream>>>(xb, zb, ln1s + l * D, ln1b + l * D);
    // W1 (+relu): xb -> midb
    k_gemm_mfma<true, true><<<dim3(NTOK / 128, 2), 256, 0, stream>>>(
        xb, w1b + (size_t)l * 256 * 128, b1 + l * HF, midb, NTOK, HF, D);
    // W2: midb -> zb
    k_gemm_mfma<false, true><<<dim3(NTOK / 128, 1), 256, 0, stream>>>(
        midb, w2b + (size_t)l * 128 * 256, b2 + l * D, zb, NTOK, D, HF);
    // x = LN(x + zb)
    k_add_ln<<<dim3(NTOK / 4), 256, 0, stream>>>(xb, zb, ln2s + l * D, ln2b + l * D);
  }

  k_gemm_mfma<false, true><<<dim3(NTOK / 128, 2), 256, 0, stream>>>(
      xb, wpb, bp, featb, NTOK, HF, D);
  k_proto_accum<<<dim3(NSUP / 256), 256, 0, stream>>>(featb, sup_out, sup_msk, psum, pcnt);
  k_proto_final<<<dim3(NC), 256, 0, stream>>>(psum, pcnt, protos);
  k_logits<<<dim3((SEQ * NC + 255) / 256), 256, 0, stream>>>(featb, protos, outp);
}

// Round 9
// 989.205 us; speedup vs baseline: 1.0764x; 1.0104x over previous
//
#include <hip/hip_runtime.h>
#include <hip/hip_bf16.h>

constexpr int D    = 128;   // d_model
constexpr int HF   = 256;   // ffn / out dim
constexpr int NH   = 4;
constexpr int DH   = 32;
constexpr int NL   = 3;
constexpr int SEQ  = 1024;
constexpr int NB   = 65;    // 64 support + 1 query
constexpr int NTOK = NB * SEQ;   // 66560
constexpr int NSUP = 64 * SEQ;   // 65536
constexpr int NC   = 10;

using u16 = unsigned short;
using u32 = unsigned int;
typedef __bf16 bf16x8 __attribute__((ext_vector_type(8)));
typedef float  f32x4  __attribute__((ext_vector_type(4)));
typedef float  f32x16 __attribute__((ext_vector_type(16)));
typedef u16    u16x4  __attribute__((ext_vector_type(4)));
typedef u16    u16x8  __attribute__((ext_vector_type(8)));
typedef u32    u32x2  __attribute__((ext_vector_type(2)));

static __device__ __forceinline__ u16 f2b(float f) {
  return __builtin_bit_cast(u16, (__bf16)f);
}
static __device__ __forceinline__ float b2f(u16 u) {
  return (float)__builtin_bit_cast(__bf16, u);
}

// ---------------- all weights f32 -> bf16 (single launch; outputs contiguous) ----
// segments: wqkv 147456 | wo 49152 | w1 98304 | w2 98304 | wp 32768  (total 425984)
__global__ __launch_bounds__(256) void k_f2b_all(const float* __restrict__ w0,
                                                 const float* __restrict__ w1,
                                                 const float* __restrict__ w2,
                                                 const float* __restrict__ w3,
                                                 const float* __restrict__ w4,
                                                 u16* __restrict__ out) {
  int i = blockIdx.x * 256 + threadIdx.x;
  const float* src; int off;
  if      (i < 147456) { src = w0; off = i; }
  else if (i < 196608) { src = w1; off = i - 147456; }
  else if (i < 294912) { src = w2; off = i - 196608; }
  else if (i < 393216) { src = w3; off = i - 294912; }
  else                 { src = w4; off = i - 393216; }
  out[i] = f2b(src[off]);
}

// ---------------- embedding -> bf16 x ----------------
__global__ __launch_bounds__(256) void k_embed(const int* __restrict__ sup,
                                               const int* __restrict__ qry,
                                               const float* __restrict__ emb,
                                               u32* __restrict__ xbw) {
  int i = blockIdx.x * 256 + threadIdx.x;          // over NTOK*64
  int tok = i >> 6;
  int d2 = (i & 63) * 2;
  int t = tok < NSUP ? sup[tok] : qry[tok - NSUP];
  float2 e = *(const float2*)(emb + t * D + d2);
  xbw[i] = (u32)f2b(e.x) | ((u32)f2b(e.y) << 16);
}

// ---------------- MFMA GEMM: C[m,n] = sum_k A[m,k]*B[n,k] + bias[n] ----------------
// grid (Ntiles, Mtiles): consecutive blocks share the A panel (L1/L2 locality).
template<bool RELU, bool BF16OUT>
__global__ __launch_bounds__(256) void k_gemm_mfma(const u16* __restrict__ A,
                                                   const u16* __restrict__ B,
                                                   const float* __restrict__ bias,
                                                   void* __restrict__ Cm,
                                                   int M, int N, int K) {
  const int tid = threadIdx.x;
  const int w = tid >> 6, l = tid & 63;
  const int g = l >> 4, c16 = l & 15;
  const int m0 = blockIdx.y * 128 + w * 32;
  const int n0 = blockIdx.x * 128;

  f32x4 acc[2][8] = {};
  const u16* a0p = A + (size_t)(m0 + c16) * K + g * 8;
  const u16* a1p = a0p + (size_t)16 * K;
  const u16* bp  = B + (size_t)(n0 + c16) * K + g * 8;

  for (int k = 0; k < K; k += 32) {
    bf16x8 a0 = *(const bf16x8*)(a0p + k);
    bf16x8 a1 = *(const bf16x8*)(a1p + k);
    #pragma unroll
    for (int nc = 0; nc < 8; ++nc) {
      bf16x8 b = *(const bf16x8*)(bp + (size_t)(nc * 16) * K + k);
      acc[0][nc] = __builtin_amdgcn_mfma_f32_16x16x32_bf16(a0, b, acc[0][nc], 0, 0, 0);
      acc[1][nc] = __builtin_amdgcn_mfma_f32_16x16x32_bf16(a1, b, acc[1][nc], 0, 0, 0);
    }
  }

  #pragma unroll
  for (int nc = 0; nc < 8; ++nc) {
    const int n_ = n0 + nc * 16 + c16;
    const float bs = bias[n_];
    #pragma unroll
    for (int mf = 0; mf < 2; ++mf)
      #pragma unroll
      for (int r = 0; r < 4; ++r) {
        const int m_ = m0 + mf * 16 + g * 4 + r;
        float v = acc[mf][nc][r] + bs;
        if (RELU) v = fmaxf(v, 0.f);
        if (BF16OUT) ((u16*)Cm)[(size_t)m_ * N + n_] = f2b(v);
        else         ((float*)Cm)[(size_t)m_ * N + n_] = v;
      }
  }
}

// ---------------- MFMA flash attention: 4 heads/block, XCD-pinned batches -----
// qkvb: bf16 [NTOK][384] = [q|k|v]; out: bf16 [NTOK][128].
// 1-D grid 2304: b=(i&7)+8*((i>>3)>>5), qt=(i>>3)&31. Block = 4 autonomous waves
// (wave = head), LDS 18432 B -> 7-8 blocks/CU (occupancy fix vs round 8's 4).
__global__ __launch_bounds__(256) void k_attn_mfma(const u16* __restrict__ qkvb,
                                                   u16* __restrict__ out) {
  const int i = blockIdx.x;
  const int b = (i & 7) + (((i >> 3) >> 5) << 3);
  if (b >= NB) return;
  const int qt = (i >> 3) & 31;
  const int tid = threadIdx.x;
  const int h = tid >> 6;         // wave = head
  const int l = tid & 63;
  const int q5 = l & 31;
  const int hi = l >> 5;          // lane half
  const int qbase = qt * 32;

  __shared__ u16 VtAll[4][2304];  // per-wave V^T [dh][key], stride 72; 18432 B total
  u16* Vt = VtAll[h];
  u32* Vtw = (u32*)Vt;

  const size_t tok0 = (size_t)b * SEQ;
  constexpr float KSL = 0.25500446f;   // 1/sqrt(32) * log2(e)

  const u16* qrow = qkvb + (tok0 + qbase + q5) * 384 + h * 32 + hi * 8;
  bf16x8 qf0 = *(const bf16x8*)(qrow);
  bf16x8 qf1 = *(const bf16x8*)(qrow + 16);

  f32x16 acc = {};                // O^T accumulator
  float m = -3.0e38f, lsum = 0.f;

  const u16* kbase = qkvb + tok0 * 384 + 128 + h * 32 + (size_t)q5 * 384 + hi * 8;
  const u16* vbase = qkvb + tok0 * 384 + 256 + h * 32 + hi * 16;
  const f32x16 z16 = {};

  for (int kt = 0; kt < SEQ; kt += 64) {
    const u16* vr0 = vbase + (size_t)(kt + q5 * 2) * 384;
    const u16* vr1 = vr0 + 384;
    u16x8 a_lo = *(const u16x8*)(vr0);
    u16x8 a_hi = *(const u16x8*)(vr0 + 8);
    u16x8 b_lo = *(const u16x8*)(vr1);
    u16x8 b_hi = *(const u16x8*)(vr1 + 8);
    const u16* kr = kbase + (size_t)kt * 384;
    bf16x8 k00 = *(const bf16x8*)(kr);
    bf16x8 k01 = *(const bf16x8*)(kr + 16);
    bf16x8 k10 = *(const bf16x8*)(kr + (size_t)32 * 384);
    bf16x8 k11 = *(const bf16x8*)(kr + (size_t)32 * 384 + 16);

    #pragma unroll
    for (int j = 0; j < 8; ++j) {
      Vtw[(hi * 16 + j) * 36 + q5]     = (u32)a_lo[j] | ((u32)b_lo[j] << 16);
      Vtw[(hi * 16 + 8 + j) * 36 + q5] = (u32)a_hi[j] | ((u32)b_hi[j] << 16);
    }
    __threadfence_block();
    __builtin_amdgcn_sched_barrier(0);

    f32x16 s0 = __builtin_amdgcn_mfma_f32_32x32x16_bf16(k00, qf0, z16, 0, 0, 0);
    s0 = __builtin_amdgcn_mfma_f32_32x32x16_bf16(k01, qf1, s0, 0, 0, 0);
    f32x16 s1 = __builtin_amdgcn_mfma_f32_32x32x16_bf16(k10, qf0, z16, 0, 0, 0);
    s1 = __builtin_amdgcn_mfma_f32_32x32x16_bf16(k11, qf1, s1, 0, 0, 0);

    float r8[8];
    #pragma unroll
    for (int ii = 0; ii < 8; ++ii)
      r8[ii] = fmaxf(fmaxf(s0[ii], s0[ii + 8]), fmaxf(s1[ii], s1[ii + 8]));
    float mx = fmaxf(fmaxf(fmaxf(r8[0], r8[1]), fmaxf(r8[2], r8[3])),
                     fmaxf(fmaxf(r8[4], r8[5]), fmaxf(r8[6], r8[7])));
    mx = fmaxf(mx, __shfl_xor(mx, 32));
    float mxk = mx * KSL;

    if (__any(mxk > m + 8.f)) {
      float mn = fmaxf(m, mxk);
      float c0 = exp2f(m - mn);
      m = mn;
      lsum *= c0;
      #pragma unroll
      for (int ii = 0; ii < 16; ++ii) acc[ii] *= c0;
    }

    float p0[16], p1[16];
    #pragma unroll
    for (int ii = 0; ii < 16; ++ii) p0[ii] = exp2f(fmaf(s0[ii], KSL, -m));
    #pragma unroll
    for (int ii = 0; ii < 16; ++ii) p1[ii] = exp2f(fmaf(s1[ii], KSL, -m));

    float t8[8];
    #pragma unroll
    for (int ii = 0; ii < 8; ++ii)
      t8[ii] = (p0[ii] + p0[ii + 8]) + (p1[ii] + p1[ii + 8]);
    float ps = ((t8[0] + t8[1]) + (t8[2] + t8[3])) + ((t8[4] + t8[5]) + (t8[6] + t8[7]));
    ps += __shfl_xor(ps, 32);
    lsum += ps;

    u32 pk0[8], pk1[8];
    #pragma unroll
    for (int mi = 0; mi < 8; ++mi) {
      pk0[mi] = (u32)f2b(p0[2 * mi]) | ((u32)f2b(p0[2 * mi + 1]) << 16);
      pk1[mi] = (u32)f2b(p1[2 * mi]) | ((u32)f2b(p1[2 * mi + 1]) << 16);
    }

    // PV: half-exchange via v_permlane32_swap_b32 (2 per fragment, no selects):
    // swap(a,c).x = l<32 ? a(l) : c(l-32);  swap(a,c).y = l<32 ? a(l+32) : c(l)
    #pragma unroll
    for (int t = 0; t < 2; ++t) {
      #pragma unroll
      for (int hh = 0; hh < 2; ++hh) {
        u32 a0w = t ? pk1[4 * hh + 0] : pk0[4 * hh + 0];
        u32 a1w = t ? pk1[4 * hh + 1] : pk0[4 * hh + 1];
        u32 a2w = t ? pk1[4 * hh + 2] : pk0[4 * hh + 2];
        u32 a3w = t ? pk1[4 * hh + 3] : pk0[4 * hh + 3];
        u32x2 r02 = __builtin_amdgcn_permlane32_swap(a0w, a2w, false, false);
        u32x2 r13 = __builtin_amdgcn_permlane32_swap(a1w, a3w, false, false);
        union { u32 w[4]; bf16x8 v; } pf;
        pf.w[0] = r02.x; pf.w[1] = r13.x; pf.w[2] = r02.y; pf.w[3] = r13.y;
        bf16x8 vf = *(const bf16x8*)(Vt + (size_t)q5 * 72 + t * 32 + hh * 16 + hi * 8);
        acc = __builtin_amdgcn_mfma_f32_32x32x16_bf16(vf, pf.v, acc, 0, 0, 0);
      }
    }
    __threadfence_block();
    __builtin_amdgcn_sched_barrier(0);
  }

  float inv = 1.f / lsum;
  u16* orow = out + (tok0 + qbase + q5) * 128 + h * 32 + hi * 4;
  #pragma unroll
  for (int a = 0; a < 4; ++a) {
    u16x4 st;
    #pragma unroll
    for (int j = 0; j < 4; ++j) st[j] = f2b(acc[a * 4 + j] * inv);
    *(u16x4*)(orow + a * 8) = st;
  }
}

// ---------------- residual add + LayerNorm (bf16 stream, f32 math) ----------------
__global__ __launch_bounds__(256) void k_add_ln(u16* __restrict__ xb,
                                                const u16* __restrict__ yb,
                                                const float* __restrict__ gamma,
                                                const float* __restrict__ beta) {
  int row = blockIdx.x * 4 + (threadIdx.x >> 6);
  int lane = threadIdx.x & 63;
  u32* xr = (u32*)(xb + (size_t)row * D);
  const u32* yr = (const u32*)(yb + (size_t)row * D);
  u32 xv = xr[lane], yv = yr[lane];
  float a = b2f((u16)(xv & 0xffff)) + b2f((u16)(yv & 0xffff));
  float b = b2f((u16)(xv >> 16))    + b2f((u16)(yv >> 16));
  float sum = a + b;
  #pragma unroll
  for (int off = 32; off; off >>= 1) sum += __shfl_xor(sum, off);
  float mean = sum * (1.f / 128.f);
  float da = a - mean, db = b - mean;
  float vs = da * da + db * db;
  #pragma unroll
  for (int off = 32; off; off >>= 1) vs += __shfl_xor(vs, off);
  float inv = 1.f / sqrtf(vs * (1.f / 128.f) + 1e-5f);
  float ox = da * inv * gamma[lane * 2 + 0] + beta[lane * 2 + 0];
  float oy = db * inv * gamma[lane * 2 + 1] + beta[lane * 2 + 1];
  xr[lane] = (u32)f2b(ox) | ((u32)f2b(oy) << 16);
}

// ---------------- prototype accumulation (bf16 feat) ----------------
__global__ __launch_bounds__(256) void k_proto_accum(const u16* __restrict__ feat,
                                                     const int* __restrict__ cls,
                                                     const int* __restrict__ msk,
                                                     float* __restrict__ psum,
                                                     int* __restrict__ pcnt) {
  __shared__ float ls[NC][HF];
  __shared__ int lc[NC];
  int tid = threadIdx.x;
  #pragma unroll
  for (int c = 0; c < NC; ++c) ls[c][tid] = 0.f;
  if (tid < NC) lc[tid] = 0;
  __syncthreads();
  int t0 = blockIdx.x * 256;
  for (int t = t0; t < t0 + 256; ++t) {
    int cl = cls[t];
    int mk = msk[t];
    if (mk > 0 && cl < NC) {
      ls[cl][tid] += b2f(feat[(size_t)t * HF + tid]);
      if (tid == 0) lc[cl]++;
    }
  }
  __syncthreads();
  for (int c = 0; c < NC; ++c) atomicAdd(&psum[c * HF + tid], ls[c][tid]);
  if (tid < NC) atomicAdd(&pcnt[tid], lc[tid]);
}

__global__ void k_proto_final(const float* __restrict__ psum,
                              const int* __restrict__ pcnt,
                              float* __restrict__ protos) {
  int c = blockIdx.x, h = threadIdx.x;
  int n = pcnt[c];
  protos[c * HF + h] = (n > 0) ? psum[c * HF + h] / (float)n : 0.f;
}

// ---------------- logits ----------------
__global__ __launch_bounds__(256) void k_logits(const u16* __restrict__ feat,
                                                const float* __restrict__ protos,
                                                float* __restrict__ out) {
  int i = blockIdx.x * 256 + threadIdx.x;
  if (i >= SEQ * NC) return;
  int s = i / NC, c = i % NC;
  const u16* qf = feat + (size_t)(NSUP + s) * HF;
  const float* pr = protos + c * HF;
  float acc = 0.f;
  #pragma unroll 8
  for (int h = 0; h < HF; ++h) {
    float d = b2f(qf[h]) - pr[h];
    acc += d * d;
  }
  out[i] = -acc;
}

extern "C" void kernel_launch(void* const* d_in, const int* in_sizes, int n_in,
                              void* d_out, int out_size, void* d_ws, size_t ws_size,
                              hipStream_t stream) {
  const int*   sup_in  = (const int*)d_in[0];
  const int*   sup_out = (const int*)d_in[1];
  const int*   qry_in  = (const int*)d_in[2];
  const int*   sup_msk = (const int*)d_in[3];
  const float* emb     = (const float*)d_in[4];
  const float* Wqkv    = (const float*)d_in[5];
  const float* bqkv    = (const float*)d_in[6];
  const float* Wo      = (const float*)d_in[7];
  const float* bo      = (const float*)d_in[8];
  const float* ln1s    = (const float*)d_in[9];
  const float* ln1b    = (const float*)d_in[10];
  const float* W1      = (const float*)d_in[11];
  const float* b1      = (const float*)d_in[12];
  const float* W2      = (const float*)d_in[13];
  const float* b2      = (const float*)d_in[14];
  const float* ln2s    = (const float*)d_in[15];
  const float* ln2b    = (const float*)d_in[16];
  const float* Wp      = (const float*)d_in[17];
  const float* bp      = (const float*)d_in[18];

  // bf16 stream: xb[NTOK,128] | yb[NTOK,128] | zb[NTOK,128] | U[NTOK,384] | weights
  u16* xb = (u16*)d_ws;
  u16* yb = xb + (size_t)NTOK * D;
  u16* zb = yb + (size_t)NTOK * D;              // Wo/W2 output
  u16* U  = zb + (size_t)NTOK * D;
  u16* qkvb  = U;                                // [NTOK,384]
  u16* midb  = U;                                // [NTOK,256] (qkvb dead)
  u16* featb = U;                                // [NTOK,256]
  u16* wqkvb = U + (size_t)NTOK * 384;
  u16* wob   = wqkvb + 3 * 384 * 128;
  u16* w1b   = wob + 3 * 128 * 128;
  u16* w2b   = w1b + 3 * 256 * 128;
  u16* wpb   = w2b + 3 * 128 * 256;
  float* psum  = (float*)(((size_t)(wpb + 256 * 128) + 15) & ~(size_t)15);
  int*   pcnt  = (int*)(psum + NC * HF);
  float* protos = psum + NC * HF + 16;
  float* outp = (float*)d_out;

  hipMemsetAsync(psum, 0, NC * HF * sizeof(float) + 16 * sizeof(int), stream);

  k_f2b_all<<<dim3(1664), 256, 0, stream>>>(Wqkv, Wo, W1, W2, Wp, wqkvb);

  k_embed<<<dim3((NTOK * 64) / 256), 256, 0, stream>>>(sup_in, qry_in, emb, (u32*)xb);

  for (int l = 0; l < NL; ++l) {
    // QKV: xb -> qkvb
    k_gemm_mfma<false, true><<<dim3(3, NTOK / 128), 256, 0, stream>>>(
        xb, wqkvb + (size_t)l * 384 * 128, bqkv + l * 384, qkvb, NTOK, 384, D);
    // attention: qkvb -> yb
    k_attn_mfma<<<dim3(2304), 256, 0, stream>>>(qkvb, yb);
    // Wo: yb -> zb
    k_gemm_mfma<false, true><<<dim3(1, NTOK / 128), 256, 0, stream>>>(
        yb, wob + (size_t)l * 128 * 128, bo + l * D, zb, NTOK, D, D);
    // x = LN(x + zb)
    k_add_ln<<<dim3(NTOK / 4), 256, 0, stream>>>(xb, zb, ln1s + l * D, ln1b + l * D);
    // W1 (+relu): xb -> midb
    k_gemm_mfma<true, true><<<dim3(2, NTOK / 128), 256, 0, stream>>>(
        xb, w1b + (size_t)l * 256 * 128, b1 + l * HF, midb, NTOK, HF, D);
    // W2: midb -> zb
    k_gemm_mfma<false, true><<<dim3(1, NTOK / 128), 256, 0, stream>>>(
        midb, w2b + (size_t)l * 128 * 256, b2 + l * D, zb, NTOK, D, HF);
    // x = LN(x + zb)
    k_add_ln<<<dim3(NTOK / 4), 256, 0, stream>>>(xb, zb, ln2s + l * D, ln2b + l * D);
  }

  k_gemm_mfma<false, true><<<dim3(2, NTOK / 128), 256, 0, stream>>>(
      xb, wpb, bp, featb, NTOK, HF, D);
  k_proto_accum<<<dim3(NSUP / 256), 256, 0, stream>>>(featb, sup_out, sup_msk, psum, pcnt);
  k_proto_final<<<dim3(NC), 256, 0, stream>>>(psum, pcnt, protos);
  k_logits<<<dim3((SEQ * NC + 255) / 256), 256, 0, stream>>>(featb, protos, outp);
}